// Round 5
// baseline (740.486 us; speedup 1.0000x reference)
//
#include <hip/hip_runtime.h>
#include <math.h>

#define F 128
#define NLAYERS 2

typedef __attribute__((ext_vector_type(8))) short bf16x8s;
typedef __attribute__((ext_vector_type(4))) float f32x4;

__device__ __forceinline__ float sigmoidf_(float x) { return 1.0f / (1.0f + expf(-x)); }

__device__ __forceinline__ unsigned short f2bf(float f) {
    unsigned int u = __float_as_uint(f);
    u += 0x7fffu + ((u >> 16) & 1u);  // RNE
    return (unsigned short)(u >> 16);
}
__device__ __forceinline__ float bf2f(unsigned short s) {
    return __uint_as_float(((unsigned int)s) << 16);
}

// ---------------------------------------------------------------------------
// Weight pack: f32 [L][3][256][128] -> bf16 k-octet layout.
//  W1b [L][64][256][8]: gates (r|u) as 256 cols, K=512 parts (x,h,agg_x,agg_h)
//  W2b [L][64][128][8]: gate c, K parts (x, rh, agg_x, agg_rh)
// ---------------------------------------------------------------------------
__global__ void pack_w_bf16(const float* __restrict__ Ws, const float* __restrict__ Wn,
                            unsigned short* __restrict__ W1b, unsigned short* __restrict__ W2b) {
    int t = blockIdx.x * blockDim.x + threadIdx.x;
    const int n1 = 2 * 64 * 256 * 8;  // 262144
    if (t < n1) {
        int j = t & 7, n = (t >> 3) & 255, ko = (t >> 11) & 63, l = t >> 17;
        int k = ko * 8 + j;
        int p = k >> 7, r = k & 127, g = n >> 7, c = n & 127;
        const float* W = (p < 2) ? Ws : Wn;
        W1b[t] = f2bf(W[(((l * 3 + g) * 256) + ((p & 1) * 128 + r)) * 128 + c]);
    } else {
        int t2 = t - n1;
        if (t2 >= 2 * 64 * 128 * 8) return;
        int j = t2 & 7, n = (t2 >> 3) & 127, ko = (t2 >> 10) & 63, l = t2 >> 16;
        int k = ko * 8 + j;
        int p = k >> 7, r = k & 127;
        const float* W = (p < 2) ? Ws : Wn;
        W2b[t2] = f2bf(W[(((l * 3 + 2) * 256) + ((p & 1) * 128 + r)) * 128 + n]);
    }
}

// f32 -> bf16 row-major copy (float4 in, ushort4 out)
__global__ void cvt_bf16(const float* __restrict__ in, unsigned short* __restrict__ out, int n4) {
    int t = blockIdx.x * blockDim.x + threadIdx.x;
    if (t >= n4) return;
    float4 v = reinterpret_cast<const float4*>(in)[t];
    ushort4 o;
    o.x = f2bf(v.x); o.y = f2bf(v.y); o.z = f2bf(v.z); o.w = f2bf(v.w);
    reinterpret_cast<ushort4*>(out)[t] = o;
}

// ---------------------------------------------------------------------------
// CSR build
// ---------------------------------------------------------------------------
__global__ void hist_dst(const int* __restrict__ dst, int* __restrict__ cnt, int E) {
    int e = blockIdx.x * blockDim.x + threadIdx.x;
    if (e < E) atomicAdd(&cnt[dst[e]], 1);
}

__global__ __launch_bounds__(1024) void scan_offs(const int* __restrict__ cnt,
                                                  int* __restrict__ offs,
                                                  int* __restrict__ cursor, int n) {
    __shared__ int wsum[16];
    __shared__ int carry_s;
    int tid = threadIdx.x;
    int lane = tid & 63, wid = tid >> 6;
    if (tid == 0) carry_s = 0;
    __syncthreads();
    for (int base = 0; base < n; base += 1024) {
        int i = base + tid;
        int v = (i < n) ? cnt[i] : 0;
        int incl = v;
#pragma unroll
        for (int off = 1; off < 64; off <<= 1) {
            int t = __shfl_up(incl, off, 64);
            if (lane >= off) incl += t;
        }
        if (lane == 63) wsum[wid] = incl;
        __syncthreads();
        if (wid == 0) {
            int s = (lane < 16) ? wsum[lane] : 0;
#pragma unroll
            for (int off = 1; off < 16; off <<= 1) {
                int t = __shfl_up(s, off, 64);
                if (lane >= off) s += t;
            }
            if (lane < 16) wsum[lane] = s;
        }
        __syncthreads();
        int wbase = (wid > 0) ? wsum[wid - 1] : 0;
        int carry = carry_s;
        int excl = carry + wbase + incl - v;
        if (i < n) { offs[i] = excl; cursor[i] = excl; }
        __syncthreads();
        if (tid == 1023) carry_s = carry + wsum[15];
        __syncthreads();
    }
    if (threadIdx.x == 0) offs[n] = carry_s;
}

__global__ void scatter_edges(const int* __restrict__ src, const int* __restrict__ dst,
                              const float* __restrict__ ew, int* __restrict__ cursor,
                              int2* __restrict__ es, int E) {
    int e = blockIdx.x * blockDim.x + threadIdx.x;
    if (e >= E) return;
    int d = dst[e];
    int p = atomicAdd(&cursor[d], 1);
    es[p] = make_int2(src[e], __float_as_int(ew[e]));
}

// ---------------------------------------------------------------------------
// CSR aggregation over bf16 tables: 32 lanes/node, ushort4 (8B) per lane,
// unroll-2 with dual accumulators for MLP. f32 accumulate, bf16 store.
// ---------------------------------------------------------------------------
__global__ __launch_bounds__(256) void agg_csr2_b(
    const unsigned short* __restrict__ V0, const unsigned short* __restrict__ V1,
    const int2* __restrict__ es, const int* __restrict__ offs,
    unsigned short* __restrict__ agg0, unsigned short* __restrict__ agg1, int N) {
    int node = blockIdx.x * 8 + (threadIdx.x >> 5);
    if (node >= N) return;
    int lane = threadIdx.x & 31;
    int beg = offs[node], end = offs[node + 1];
    float p0[4] = {0, 0, 0, 0}, q0[4] = {0, 0, 0, 0};
    float p1[4] = {0, 0, 0, 0}, q1[4] = {0, 0, 0, 0};
    int i = beg;
    for (; i + 1 < end; i += 2) {
        int2 e0 = es[i], e1 = es[i + 1];
        float w0 = __int_as_float(e0.y), w1 = __int_as_float(e1.y);
        size_t r0 = ((size_t)e0.x << 7) + (lane << 2);
        size_t r1 = ((size_t)e1.x << 7) + (lane << 2);
        ushort4 x0 = *reinterpret_cast<const ushort4*>(V0 + r0);
        ushort4 x1 = *reinterpret_cast<const ushort4*>(V0 + r1);
        ushort4 h0 = *reinterpret_cast<const ushort4*>(V1 + r0);
        ushort4 h1 = *reinterpret_cast<const ushort4*>(V1 + r1);
        p0[0] += w0 * bf2f(x0.x); p0[1] += w0 * bf2f(x0.y);
        p0[2] += w0 * bf2f(x0.z); p0[3] += w0 * bf2f(x0.w);
        p1[0] += w1 * bf2f(x1.x); p1[1] += w1 * bf2f(x1.y);
        p1[2] += w1 * bf2f(x1.z); p1[3] += w1 * bf2f(x1.w);
        q0[0] += w0 * bf2f(h0.x); q0[1] += w0 * bf2f(h0.y);
        q0[2] += w0 * bf2f(h0.z); q0[3] += w0 * bf2f(h0.w);
        q1[0] += w1 * bf2f(h1.x); q1[1] += w1 * bf2f(h1.y);
        q1[2] += w1 * bf2f(h1.z); q1[3] += w1 * bf2f(h1.w);
    }
    if (i < end) {
        int2 e0 = es[i];
        float w0 = __int_as_float(e0.y);
        size_t r0 = ((size_t)e0.x << 7) + (lane << 2);
        ushort4 x0 = *reinterpret_cast<const ushort4*>(V0 + r0);
        ushort4 h0 = *reinterpret_cast<const ushort4*>(V1 + r0);
        p0[0] += w0 * bf2f(x0.x); p0[1] += w0 * bf2f(x0.y);
        p0[2] += w0 * bf2f(x0.z); p0[3] += w0 * bf2f(x0.w);
        q0[0] += w0 * bf2f(h0.x); q0[1] += w0 * bf2f(h0.y);
        q0[2] += w0 * bf2f(h0.z); q0[3] += w0 * bf2f(h0.w);
    }
    size_t ob = ((size_t)node << 7) + (lane << 2);
    ushort4 o0, o1;
    o0.x = f2bf(p0[0] + p1[0]); o0.y = f2bf(p0[1] + p1[1]);
    o0.z = f2bf(p0[2] + p1[2]); o0.w = f2bf(p0[3] + p1[3]);
    o1.x = f2bf(q0[0] + q1[0]); o1.y = f2bf(q0[1] + q1[1]);
    o1.z = f2bf(q0[2] + q1[2]); o1.w = f2bf(q0[3] + q1[3]);
    *reinterpret_cast<ushort4*>(agg0 + ob) = o0;
    *reinterpret_cast<ushort4*>(agg1 + ob) = o1;
}

__global__ __launch_bounds__(256) void agg_csr1_b(
    const unsigned short* __restrict__ V0,
    const int2* __restrict__ es, const int* __restrict__ offs,
    unsigned short* __restrict__ agg0, int N) {
    int node = blockIdx.x * 8 + (threadIdx.x >> 5);
    if (node >= N) return;
    int lane = threadIdx.x & 31;
    int beg = offs[node], end = offs[node + 1];
    float p0[4] = {0, 0, 0, 0}, p1[4] = {0, 0, 0, 0};
    int i = beg;
    for (; i + 1 < end; i += 2) {
        int2 e0 = es[i], e1 = es[i + 1];
        float w0 = __int_as_float(e0.y), w1 = __int_as_float(e1.y);
        size_t r0 = ((size_t)e0.x << 7) + (lane << 2);
        size_t r1 = ((size_t)e1.x << 7) + (lane << 2);
        ushort4 x0 = *reinterpret_cast<const ushort4*>(V0 + r0);
        ushort4 x1 = *reinterpret_cast<const ushort4*>(V0 + r1);
        p0[0] += w0 * bf2f(x0.x); p0[1] += w0 * bf2f(x0.y);
        p0[2] += w0 * bf2f(x0.z); p0[3] += w0 * bf2f(x0.w);
        p1[0] += w1 * bf2f(x1.x); p1[1] += w1 * bf2f(x1.y);
        p1[2] += w1 * bf2f(x1.z); p1[3] += w1 * bf2f(x1.w);
    }
    if (i < end) {
        int2 e0 = es[i];
        float w0 = __int_as_float(e0.y);
        size_t r0 = ((size_t)e0.x << 7) + (lane << 2);
        ushort4 x0 = *reinterpret_cast<const ushort4*>(V0 + r0);
        p0[0] += w0 * bf2f(x0.x); p0[1] += w0 * bf2f(x0.y);
        p0[2] += w0 * bf2f(x0.z); p0[3] += w0 * bf2f(x0.w);
    }
    size_t ob = ((size_t)node << 7) + (lane << 2);
    ushort4 o0;
    o0.x = f2bf(p0[0] + p1[0]); o0.y = f2bf(p0[1] + p1[1]);
    o0.z = f2bf(p0[2] + p1[2]); o0.w = f2bf(p0[3] + p1[3]);
    *reinterpret_cast<ushort4*>(agg0 + ob) = o0;
}

// ---------------------------------------------------------------------------
// Barrier-free MFMA GEMM: NO LDS. Each lane loads its 16B A and B fragments
// straight from global (A: row-major bf16; B: k-octet layout -> both are
// contiguous dwordx4 loads; B is L2-resident). 128x128 tile, 4 waves (2x2),
// each wave 64x64 = 4x4 frags of 16x16x32 bf16 MFMA. Zero __syncthreads().
// mode 0 (ru): col<128 -> rhb = bf16(sigmoid*h); col>=128 -> u = sigmoid (f32)
// mode 1 (c):  c = sigmoid; hn = u*h+(1-u)*c -> outf (+outf2), outb = bf16(hn)
// ---------------------------------------------------------------------------
__global__ __launch_bounds__(256) void gemm_mfma(
    const unsigned short* __restrict__ A0, const unsigned short* __restrict__ A1,
    const unsigned short* __restrict__ A2, const unsigned short* __restrict__ A3,
    const unsigned short* __restrict__ Wb, const float* __restrict__ bias,
    const float* __restrict__ hfull, const float* __restrict__ uin,
    unsigned short* __restrict__ outb, float* __restrict__ outf,
    float* __restrict__ outf2, int Nn, int Ntot, int mode) {
    const unsigned short* parts[4] = {A0, A1, A2, A3};

    int tid = threadIdx.x;
    int row0 = blockIdx.x * 128;
    int n0c = blockIdx.y * 128;
    int lane = tid & 63;
    int w = tid >> 6;
    int wrow = (w & 1) << 6;       // 0 / 64
    int wcol = (w >> 1) << 6;      // 0 / 64
    int quad = lane >> 4, l16 = lane & 15;

    // Per-lane fragment addresses
    int rowA[4];
#pragma unroll
    for (int mt = 0; mt < 4; ++mt) {
        int r = row0 + wrow + (mt << 4) + l16;
        rowA[mt] = (r < Nn) ? r : (Nn - 1);
    }
    int colB[4];
#pragma unroll
    for (int nt = 0; nt < 4; ++nt) colB[nt] = n0c + wcol + (nt << 4) + l16;

    f32x4 acc[4][4];
    const f32x4 z4 = {0.f, 0.f, 0.f, 0.f};
#pragma unroll
    for (int mt = 0; mt < 4; ++mt)
#pragma unroll
        for (int nt = 0; nt < 4; ++nt) acc[mt][nt] = z4;

#pragma unroll
    for (int ks = 0; ks < 512; ks += 32) {
        const unsigned short* Ap = parts[ks >> 7];
        int cb = (ks & 127) + (quad << 3);           // short offset within row
        int koG = (ks >> 3) + quad;                  // k-octet index for B
        bf16x8s af[4], bfr[4];
#pragma unroll
        for (int mt = 0; mt < 4; ++mt)
            af[mt] = *reinterpret_cast<const bf16x8s*>(Ap + (((size_t)rowA[mt]) << 7) + cb);
#pragma unroll
        for (int nt = 0; nt < 4; ++nt)
            bfr[nt] = *reinterpret_cast<const bf16x8s*>(Wb + (((size_t)(koG * Ntot + colB[nt])) << 3));
#pragma unroll
        for (int mt = 0; mt < 4; ++mt)
#pragma unroll
            for (int nt = 0; nt < 4; ++nt)
                acc[mt][nt] = __builtin_amdgcn_mfma_f32_16x16x32_bf16(
                    af[mt], bfr[nt], acc[mt][nt], 0, 0, 0);
    }

    // Epilogue: row = row0 + wrow + mt*16 + quad*4 + reg; col = n0c + wcol + nt*16 + l16
#pragma unroll
    for (int mt = 0; mt < 4; ++mt) {
#pragma unroll
        for (int reg = 0; reg < 4; ++reg) {
            int row = row0 + wrow + (mt << 4) + (quad << 2) + reg;
            if (row >= Nn) continue;
#pragma unroll
            for (int nt = 0; nt < 4; ++nt) {
                int col = n0c + wcol + (nt << 4) + l16;
                float val = acc[mt][nt][reg] + bias[col];
                if (mode == 0) {
                    float sg = sigmoidf_(val);
                    int c = col & 127;
                    size_t o = ((size_t)row << 7) + c;
                    if (col < 128)
                        outb[o] = f2bf(sg * hfull[o]);   // rh = r*h (bf16)
                    else
                        outf[o] = sg;                    // u (f32)
                } else {
                    float cv = sigmoidf_(val);
                    size_t o = ((size_t)row << 7) + col;
                    float uu = uin[o];
                    float hh = hfull[o];
                    float hn = uu * hh + (1.0f - uu) * cv;
                    outf[o] = hn;
                    if (outf2) outf2[o] = hn;
                    outb[o] = f2bf(hn);                  // next layer's xb
                }
            }
        }
    }
}

// ---------------------------------------------------------------------------
extern "C" void kernel_launch(void* const* d_in, const int* in_sizes, int n_in,
                              void* d_out, int out_size, void* d_ws, size_t ws_size,
                              hipStream_t stream) {
    const float* x      = (const float*)d_in[0];
    const float* hidden = (const float*)d_in[1];
    const int*   src    = (const int*)d_in[2];
    const int*   dst    = (const int*)d_in[3];
    const float* ew     = (const float*)d_in[4];
    const float* Wself  = (const float*)d_in[5];
    const float* Wneigh = (const float*)d_in[6];
    const float* bias   = (const float*)d_in[7];
    float* out = (float*)d_out;

    int N = in_sizes[0] / F;  // 50000
    int E = in_sizes[2];      // 800000
    size_t NF = (size_t)N * F;

    char* p = (char*)d_ws;
    auto alloc = [&](size_t bytes) { char* r = p; p += (bytes + 255) & ~255ull; return r; };
    unsigned short* xb0    = (unsigned short*)alloc(NF * 2);
    unsigned short* xb1    = (unsigned short*)alloc(NF * 2);
    unsigned short* hb     = (unsigned short*)alloc(2 * NF * 2);
    unsigned short* agg_xb = (unsigned short*)alloc(NF * 2);
    unsigned short* agg_hb = (unsigned short*)alloc(NF * 2);
    unsigned short* agg_rb = (unsigned short*)alloc(NF * 2);
    unsigned short* rhb    = (unsigned short*)alloc(NF * 2);
    float*          u      = (float*)alloc(NF * 4);
    unsigned short* W1b    = (unsigned short*)alloc(2 * 64 * 256 * 8 * 2);
    unsigned short* W2b    = (unsigned short*)alloc(2 * 64 * 128 * 8 * 2);
    int2*           es     = (int2*)alloc((size_t)E * 8);
    int*            cnt    = (int*)alloc((size_t)N * 4);
    int*            offs   = (int*)alloc(((size_t)N + 1) * 4);
    int*            cursor = (int*)alloc((size_t)N * 4);

    pack_w_bf16<<<dim3(1536), dim3(256), 0, stream>>>(Wself, Wneigh, W1b, W2b);
    cvt_bf16<<<dim3((int)(NF / 4 + 255) / 256, 1), dim3(256), 0, stream>>>(x, xb0, (int)(NF / 4));
    cvt_bf16<<<dim3((int)(2 * NF / 4 + 255) / 256, 1), dim3(256), 0, stream>>>(hidden, hb, (int)(2 * NF / 4));

    hipMemsetAsync(cnt, 0, (size_t)N * sizeof(int), stream);
    int eBlocks = (E + 255) / 256;
    hist_dst<<<dim3(eBlocks), dim3(256), 0, stream>>>(dst, cnt, E);
    scan_offs<<<dim3(1), dim3(1024), 0, stream>>>(cnt, offs, cursor, N);
    scatter_edges<<<dim3(eBlocks), dim3(256), 0, stream>>>(src, dst, ew, cursor, es, E);

    float* out_x  = out;
    float* out_h1 = out + NF;
    float* out_h2 = out + 2 * NF;

    int aggBlocks = (N + 7) / 8;
    int mBlocks = (N + 127) / 128;
    for (int l = 0; l < NLAYERS; ++l) {
        const unsigned short* xbL = (l == 0) ? xb0 : xb1;
        const unsigned short* hbL = hb + (size_t)l * NF;
        const float* hL = hidden + (size_t)l * NF;
        const float* biasL = bias + (size_t)l * 384;

        agg_csr2_b<<<dim3(aggBlocks), dim3(256), 0, stream>>>(xbL, hbL, es, offs,
                                                              agg_xb, agg_hb, N);

        gemm_mfma<<<dim3(mBlocks, 2), dim3(256), 0, stream>>>(
            xbL, hbL, agg_xb, agg_hb,
            W1b + (size_t)l * 64 * 256 * 8, biasL, hL, nullptr,
            rhb, u, nullptr, N, 256, 0);

        agg_csr1_b<<<dim3(aggBlocks), dim3(256), 0, stream>>>(rhb, es, offs, agg_rb, N);

        float* o1 = (l == 0) ? out_h1 : out_h2;
        float* o2 = (l == NLAYERS - 1) ? out_x : nullptr;
        unsigned short* xbN = (l == 0) ? xb1 : xb0;  // l==1's outb is a dead scratch
        gemm_mfma<<<dim3(mBlocks, 1), dim3(256), 0, stream>>>(
            xbL, rhb, agg_xb, agg_rb,
            W2b + (size_t)l * 64 * 128 * 8, biasL + 256, hL, u,
            xbN, o1, o2, N, 128, 1);
    }
}